// Round 10
// baseline (8133.508 us; speedup 1.0000x reference)
//
#include <hip/hip_runtime.h>
#include <hip/hip_fp16.h>

#define H 1024
#define B 512
#define T 512
#define NC 10

#define NGROUPS 16      // batch-slice groups (32 batches each)
#define WPG 16          // WGs per group (M slices)
#define NSLICE 32       // batches per group
#define MROWS 64        // H rows per WG
#define FLAG_STRIDE 16  // 64B-padded flag per (WG,wave)

typedef _Float16 f16x8 __attribute__((ext_vector_type(8)));
typedef _Float16 f16x4 __attribute__((ext_vector_type(4)));
typedef float    f32x4 __attribute__((ext_vector_type(4)));
typedef unsigned u32x4 __attribute__((ext_vector_type(4)));
typedef unsigned long long ull;

__device__ __forceinline__ float fast_tanh(float x) {
    float e = __expf(2.0f * x);
    return 1.0f - 2.0f / (e + 1.0f);
}

// ---- W_hh f32 -> f16 row-major ----
__global__ void convert_w(const float* __restrict__ w, _Float16* __restrict__ o) {
    int i = (blockIdx.x * 256 + threadIdx.x) * 4;
    float4 v = *(const float4*)(w + i);
    f16x4 r;
    r[0] = (_Float16)v.x; r[1] = (_Float16)v.y;
    r[2] = (_Float16)v.z; r[3] = (_Float16)v.w;
    *(f16x4*)(o + i) = r;
}

// ---- x [B][T] -> xT [T][B] ----
__global__ void transpose_x(const float* __restrict__ x, float* __restrict__ xT) {
    __shared__ float tile[32][33];
    const int tx = threadIdx.x & 31;
    const int ty = threadIdx.x >> 5;
    const int t0 = blockIdx.x * 32;
    const int b0 = blockIdx.y * 32;
    #pragma unroll
    for (int i = ty; i < 32; i += 8)
        tile[i][tx] = x[(size_t)(b0 + i) * T + t0 + tx];
    __syncthreads();
    #pragma unroll
    for (int i = ty; i < 32; i += 8)
        xT[(size_t)(t0 + i) * B + b0 + tx] = tile[tx][i];
}

// h load: sc0 only -> bypass own stale L1, served by the XCD-shared L2
#define G_LOAD_X4(dst, addr, OFF) \
    asm volatile("global_load_dwordx4 %0, %1, off offset:" OFF " sc0" \
                 : "=&v"(dst) : "v"(addr) : "memory")

#define ISSUE8(arr, base) do { \
    G_LOAD_X4(arr[0], (base), "0");   G_LOAD_X4(arr[1], (base), "64");  \
    G_LOAD_X4(arr[2], (base), "128"); G_LOAD_X4(arr[3], (base), "192"); \
    G_LOAD_X4(arr[4], (base), "256"); G_LOAD_X4(arr[5], (base), "320"); \
    G_LOAD_X4(arr[6], (base), "384"); G_LOAD_X4(arr[7], (base), "448"); \
} while (0)

// h store: sc0 -> coherent write-through to the XCD-shared L2 (stops at L2)
#define G_STORE_X2(addr, data) \
    asm volatile("global_store_dwordx2 %0, %1, off sc0" \
                 :: "v"(addr), "v"(data) : "memory")

// ---- persistent RNN: 256 WGs x 256 thr (4 waves) ----
// Groups formed dynamically per XCD (1 WG/CU forced by 128KB LDS; grid=CUs
// => exactly 32 WGs/XCD => 2 groups of 16 WGs per XCD, sharing one L2).
// h exchange AND flags inside the XCD L2 (sc0 stores + sc0 loads — the path
// R9 proved correctness-critically). Dual-published MALL flags (R8-proven)
// provide a deadlock-free fallback for the poll.
__global__ void __launch_bounds__(256, 1) rnn_persist(
        const _Float16* __restrict__ Wf, const float* __restrict__ xT,
        const float* __restrict__ Whx, const float* __restrict__ bh,
        _Float16* h0, _Float16* h1,
        unsigned* flagsL2, unsigned* flagsMALL, unsigned* claim) {

    __shared__ _Float16 Wlds[MROWS * H];   // 128 KB -> exactly 1 WG/CU
    __shared__ int s_g, s_ms;

    const int tid  = threadIdx.x;
    const int wave = tid >> 6;
    const int lane = tid & 63;
    const int lm   = lane & 15;
    const int kg   = lane >> 4;
    const int wm   = wave >> 1;            // M half 0..1
    const int wn   = wave & 1;             // N half 0..1

    // ---- dynamic XCD grouping (capacity-forced: exactly 32 WGs per XCD) ----
    if (tid == 0) {
        unsigned xcd;
        asm volatile("s_getreg_b32 %0, hwreg(HW_REG_XCC_ID)" : "=s"(xcd));
        xcd &= 7;
        unsigned slot = atomicAdd(&claim[xcd], 1u);   // 0..31 per XCD
        s_ms = (int)(slot & 15);
        s_g  = (int)(xcd * 2 + (slot >> 4));
    }
    __syncthreads();
    const int g  = s_g;
    const int ms = s_ms;

    // ---- stage W rows [ms*64,+64) into fragment-order LDS ----
    for (int f = tid; f < MROWS * H / 8; f += 256) {
        const int p   = f >> 6;
        const int l   = f & 63;
        const int kkb = p >> 2;
        const int pwm = (p >> 1) & 1;
        const int prb = p & 1;
        const int pkg = l >> 4;
        const int plm = l & 15;
        const int m = ms * 64 + pwm * 32 + prb * 16 + plm;
        f16x8 v = *(const f16x8*)(Wf + (size_t)m * H + kkb * 32 + pkg * 8);
        *(f16x8*)((char*)Wlds + (size_t)f * 16) = v;
    }
    __syncthreads();   // once, before the loop

    // ---- per-lane constants ----
    const int n      = g * NSLICE + wn * 16 + lm;   // batch column
    const int base32 = ms * 64 + wm * 32;
    float whx0[4], whx1[4];
    #pragma unroll
    for (int r = 0; r < 4; ++r) {
        whx0[r] = Whx[base32 + kg * 4 + r];
        whx1[r] = Whx[base32 + 16 + kg * 4 + r];
    }
    const float bhn = bh[n];

    const ull hu0 = (ull)h0, hu1 = (ull)h1;
    const char* arow = (const char*)Wlds + wm * 2048 + lane * 16;

    // my flag: (g, ms, wm, wn); producers I wait on: (g, ms', wm', wn)
    const size_t fidx_me = (size_t)((((g << 4) | ms) << 2) | (wm << 1) | wn)
                           * FLAG_STRIDE;
    const size_t fidx_po = (size_t)((((g << 4) | ((lane >> 1) & 15)) << 2)
                           | ((lane & 1) << 1) | wn) * FLAG_STRIDE;
    const ull fmeL2   = (ull)(flagsL2 + fidx_me);
    unsigned* fmeMALL = flagsMALL + fidx_me;
    const ull fpollL2 = (ull)(flagsL2 + fidx_po);
    const unsigned* fpollMALL = flagsMALL + fidx_po;

    #define COMPUTE8(arr, KB0)                                            \
        _Pragma("unroll")                                                 \
        for (int i = 0; i < 8; ++i) {                                     \
            f16x8 a0 = *(const f16x8*)(arow + (KB0 + i) * 4096);          \
            f16x8 a1 = *(const f16x8*)(arow + (KB0 + i) * 4096 + 1024);   \
            union { u32x4 u; f16x8 v; } bb; bb.u = arr[i];                \
            acc0 = __builtin_amdgcn_mfma_f32_16x16x32_f16(a0, bb.v, acc0, 0, 0, 0); \
            acc1 = __builtin_amdgcn_mfma_f32_16x16x32_f16(a1, bb.v, acc1, 0, 0, 0); \
        }

    for (int t = 0; t < T; ++t) {
        // ---- wait for h(t): L2 fast path; MALL fallback (deadlock-free) ----
        for (int it = 0; ; ++it) {
            unsigned v;
            if (it < 64) {
                asm volatile("global_load_dword %0, %1, off sc0\n\t"
                             "s_waitcnt vmcnt(0)"
                             : "=&v"(v) : "v"(fpollL2) : "memory");
            } else {
                v = __hip_atomic_load(fpollMALL, __ATOMIC_RELAXED,
                                      __HIP_MEMORY_SCOPE_AGENT);
            }
            if (__all((int)(v >= (unsigned)t))) break;
            __builtin_amdgcn_s_sleep(1);
        }
        __builtin_amdgcn_sched_barrier(0);

        const ull rdb = (t & 1) ? hu1 : hu0;
        const ull wrb = (t & 1) ? hu0 : hu1;
        const ull rd  = rdb + (size_t)n * 2048 + kg * 16;

        u32x4 hA[8], hB[8];
        f32x4 acc0 = {0.f, 0.f, 0.f, 0.f};
        f32x4 acc1 = {0.f, 0.f, 0.f, 0.f};

        ISSUE8(hA, rd);
        ISSUE8(hB, rd + 512);
        asm volatile("s_waitcnt vmcnt(8)" ::: "memory");
        __builtin_amdgcn_sched_barrier(0);
        COMPUTE8(hA, 0);
        ISSUE8(hA, rd + 1024);
        asm volatile("s_waitcnt vmcnt(8)" ::: "memory");
        __builtin_amdgcn_sched_barrier(0);
        COMPUTE8(hB, 8);
        ISSUE8(hB, rd + 1536);
        asm volatile("s_waitcnt vmcnt(8)" ::: "memory");
        __builtin_amdgcn_sched_barrier(0);
        COMPUTE8(hA, 16);
        asm volatile("s_waitcnt vmcnt(0)" ::: "memory");
        __builtin_amdgcn_sched_barrier(0);
        COMPUTE8(hB, 24);

        // ---- epilogue: rank-1 input + bias + tanh; sc0 stores (-> own L2) ----
        const float xn = xT[(size_t)t * B + n];
        union { ull u; f16x4 v; } s0, s1;
        #pragma unroll
        for (int r = 0; r < 4; ++r)
            s0.v[r] = (_Float16)fast_tanh(acc0[r] + whx0[r] * xn + bhn);
        #pragma unroll
        for (int r = 0; r < 4; ++r)
            s1.v[r] = (_Float16)fast_tanh(acc1[r] + whx1[r] * xn + bhn);
        // h row-major [n][m]: s0 rows at m=base32+kg*4 (8B), s1 at m+16 (+32B)
        const ull wr = wrb + (size_t)n * 2048 + (size_t)(base32 + kg * 4) * 2;
        G_STORE_X2(wr, s0.u);
        G_STORE_X2(wr + 32, s1.u);

        // ---- signal: h in L2 (acked) -> flag via L2 (fast) + MALL (fallback) ----
        asm volatile("s_waitcnt vmcnt(0)" ::: "memory");  // reads+stores drained
        if (lane == 0) {
            const unsigned fv = (unsigned)(t + 1);
            asm volatile("global_store_dword %0, %1, off sc0"
                         :: "v"(fmeL2), "v"(fv) : "memory");
            __hip_atomic_store(fmeMALL, fv,
                               __ATOMIC_RELAXED, __HIP_MEMORY_SCOPE_AGENT);
        }
        __builtin_amdgcn_sched_barrier(0);
    }
    #undef COMPUTE8
}

// ---- final projection: h plain row-major [B][H] ----
__global__ void proj_kernel(const _Float16* __restrict__ hT,
                            const float* __restrict__ Wph,
                            const float* __restrict__ bp,
                            float* __restrict__ out) {
    const int b = blockIdx.x;
    const int lane = threadIdx.x;  // 64
    float partial[NC];
    #pragma unroll
    for (int c = 0; c < NC; ++c) partial[c] = 0.f;
    for (int i = lane; i < H; i += 64) {
        float hv = (float)hT[(size_t)b * H + i];
        #pragma unroll
        for (int c = 0; c < NC; ++c) partial[c] += Wph[(size_t)c * H + i] * hv;
    }
    #pragma unroll
    for (int c = 0; c < NC; ++c) {
        float v = partial[c];
        #pragma unroll
        for (int off = 32; off; off >>= 1) v += __shfl_down(v, off);
        if (lane == 0) out[(size_t)b * NC + c] = v + bp[b];
    }
}

extern "C" void kernel_launch(void* const* d_in, const int* in_sizes, int n_in,
                              void* d_out, int out_size, void* d_ws, size_t ws_size,
                              hipStream_t stream) {
    const float* x   = (const float*)d_in[0];
    const float* Whx = (const float*)d_in[1];
    const float* Whh = (const float*)d_in[2];
    const float* Wph = (const float*)d_in[3];
    const float* bh  = (const float*)d_in[4];
    const float* bp  = (const float*)d_in[5];
    float* out = (float*)d_out;

    char* ws = (char*)d_ws;
    _Float16* Wf       = (_Float16*)ws;                     // 2 MB
    _Float16* h0       = (_Float16*)(ws + (2u << 20));      // 1 MB
    _Float16* h1       = (_Float16*)(ws + (3u << 20));      // 1 MB
    float*    xT       = (float*)(ws + (4u << 20));         // 1 MB
    unsigned* flagsL2  = (unsigned*)(ws + (5u << 20));      // 64 KB
    unsigned* flagsMALL= (unsigned*)(ws + (5u << 20) + 65536);  // 64 KB
    unsigned* claim    = (unsigned*)(ws + (5u << 20) + 131072);

    convert_w<<<(H * H / 4) / 256, 256, 0, stream>>>(Whh, Wf);
    transpose_x<<<dim3(T / 32, B / 32), 256, 0, stream>>>(x, xT);
    hipMemsetAsync(h0, 0, (size_t)B * H * 2, stream);
    hipMemsetAsync(flagsL2, 0, 131072 + 256, stream);

    rnn_persist<<<NGROUPS * WPG, 256, 0, stream>>>(Wf, xT, Whx, bh, h0, h1,
                                                   flagsL2, flagsMALL, claim);

    // T even -> final h in h0
    proj_kernel<<<B, 64, 0, stream>>>(h0, Wph, bp, out);
}

// Round 11
// 3599.992 us; speedup vs baseline: 2.2593x; 2.2593x over previous
//
#include <hip/hip_runtime.h>
#include <hip/hip_fp16.h>

#define H 1024
#define B 512
#define T 512
#define NC 10

#define NGROUPS 16      // batch-slice groups (32 batches each)
#define WPG 16          // WGs per group (M slices)
#define NSLICE 32       // batches per group
#define MROWS 64        // H rows per WG
#define FLAG_STRIDE 16  // 64B-padded flag per (WG,wave)

typedef _Float16 f16x8 __attribute__((ext_vector_type(8)));
typedef _Float16 f16x4 __attribute__((ext_vector_type(4)));
typedef float    f32x4 __attribute__((ext_vector_type(4)));
typedef unsigned u32x4 __attribute__((ext_vector_type(4)));
typedef unsigned long long ull;

__device__ __forceinline__ float fast_tanh(float x) {
    float e = __expf(2.0f * x);
    return 1.0f - 2.0f / (e + 1.0f);
}

// ---- W_hh f32 -> f16 row-major ----
__global__ void convert_w(const float* __restrict__ w, _Float16* __restrict__ o) {
    int i = (blockIdx.x * 256 + threadIdx.x) * 4;
    float4 v = *(const float4*)(w + i);
    f16x4 r;
    r[0] = (_Float16)v.x; r[1] = (_Float16)v.y;
    r[2] = (_Float16)v.z; r[3] = (_Float16)v.w;
    *(f16x4*)(o + i) = r;
}

// ---- x [B][T] -> xT [T][B] ----
__global__ void transpose_x(const float* __restrict__ x, float* __restrict__ xT) {
    __shared__ float tile[32][33];
    const int tx = threadIdx.x & 31;
    const int ty = threadIdx.x >> 5;
    const int t0 = blockIdx.x * 32;
    const int b0 = blockIdx.y * 32;
    #pragma unroll
    for (int i = ty; i < 32; i += 8)
        tile[i][tx] = x[(size_t)(b0 + i) * T + t0 + tx];
    __syncthreads();
    #pragma unroll
    for (int i = ty; i < 32; i += 8)
        xT[(size_t)(t0 + i) * B + b0 + tx] = tile[tx][i];
}

// h load: sc0 only -> bypass own stale L1, served by the XCD-shared L2
#define G_LOAD_X4(dst, addr, OFF) \
    asm volatile("global_load_dwordx4 %0, %1, off offset:" OFF " sc0" \
                 : "=&v"(dst) : "v"(addr) : "memory")

#define ISSUE8(arr, base) do { \
    G_LOAD_X4(arr[0], (base), "0");   G_LOAD_X4(arr[1], (base), "64");  \
    G_LOAD_X4(arr[2], (base), "128"); G_LOAD_X4(arr[3], (base), "192"); \
    G_LOAD_X4(arr[4], (base), "256"); G_LOAD_X4(arr[5], (base), "320"); \
    G_LOAD_X4(arr[6], (base), "384"); G_LOAD_X4(arr[7], (base), "448"); \
} while (0)

// h store: sc0 -> coherent write-through to the XCD-shared L2 (stops at L2)
#define G_STORE_X2(addr, data) \
    asm volatile("global_store_dwordx2 %0, %1, off sc0" \
                 :: "v"(addr), "v"(data) : "memory")

// flag poll load: agent-scope (MALL) — the proven prompt-visibility path
#define POLL_ISSUE(v) \
    asm volatile("global_load_dword %0, %1, off sc0 sc1" \
                 : "=&v"(v) : "v"(fpoll) : "memory")

// ---- persistent RNN: 256 WGs x 256 thr (4 waves) ----
// R9 structure (h in XCD L2 via sc0; flags via agent-scope/MALL atomics);
// single change: pipelined sleep-free 3-deep poll ring (~300cy/sample
// instead of ~1us/sample).
__global__ void __launch_bounds__(256, 1) rnn_persist(
        const _Float16* __restrict__ Wf, const float* __restrict__ xT,
        const float* __restrict__ Whx, const float* __restrict__ bh,
        _Float16* h0, _Float16* h1, unsigned* flags, unsigned* claim) {

    __shared__ _Float16 Wlds[MROWS * H];   // 128 KB -> exactly 1 WG/CU
    __shared__ int s_g, s_ms;

    const int tid  = threadIdx.x;
    const int wave = tid >> 6;
    const int lane = tid & 63;
    const int lm   = lane & 15;
    const int kg   = lane >> 4;
    const int wm   = wave >> 1;            // M half 0..1
    const int wn   = wave & 1;             // N half 0..1

    // ---- dynamic XCD grouping (capacity-forced: exactly 32 WGs per XCD) ----
    if (tid == 0) {
        unsigned xcd;
        asm volatile("s_getreg_b32 %0, hwreg(HW_REG_XCC_ID)" : "=s"(xcd));
        xcd &= 7;
        unsigned slot = atomicAdd(&claim[xcd], 1u);   // 0..31 per XCD
        s_ms = (int)(slot & 15);
        s_g  = (int)(xcd * 2 + (slot >> 4));
    }
    __syncthreads();
    const int g  = s_g;
    const int ms = s_ms;

    // ---- stage W rows [ms*64,+64) into fragment-order LDS ----
    for (int f = tid; f < MROWS * H / 8; f += 256) {
        const int p   = f >> 6;
        const int l   = f & 63;
        const int kkb = p >> 2;
        const int pwm = (p >> 1) & 1;
        const int prb = p & 1;
        const int pkg = l >> 4;
        const int plm = l & 15;
        const int m = ms * 64 + pwm * 32 + prb * 16 + plm;
        f16x8 v = *(const f16x8*)(Wf + (size_t)m * H + kkb * 32 + pkg * 8);
        *(f16x8*)((char*)Wlds + (size_t)f * 16) = v;
    }
    __syncthreads();   // once, before the loop

    // ---- per-lane constants ----
    const int n      = g * NSLICE + wn * 16 + lm;   // batch column
    const int base32 = ms * 64 + wm * 32;
    float whx0[4], whx1[4];
    #pragma unroll
    for (int r = 0; r < 4; ++r) {
        whx0[r] = Whx[base32 + kg * 4 + r];
        whx1[r] = Whx[base32 + 16 + kg * 4 + r];
    }
    const float bhn = bh[n];

    const ull hu0 = (ull)h0, hu1 = (ull)h1;
    const char* arow = (const char*)Wlds + wm * 2048 + lane * 16;

    // my flag: (g, ms, wm, wn); producers I wait on: (g, ms', wm', wn)
    unsigned* fme = flags +
        (size_t)((((g << 4) | ms) << 2) | (wm << 1) | wn) * FLAG_STRIDE;
    const ull fpoll = (ull)(flags +
        (size_t)((((g << 4) | ((lane >> 1) & 15)) << 2) | ((lane & 1) << 1) | wn)
        * FLAG_STRIDE);

    #define COMPUTE8(arr, KB0)                                            \
        _Pragma("unroll")                                                 \
        for (int i = 0; i < 8; ++i) {                                     \
            f16x8 a0 = *(const f16x8*)(arow + (KB0 + i) * 4096);          \
            f16x8 a1 = *(const f16x8*)(arow + (KB0 + i) * 4096 + 1024);   \
            union { u32x4 u; f16x8 v; } bb; bb.u = arr[i];                \
            acc0 = __builtin_amdgcn_mfma_f32_16x16x32_f16(a0, bb.v, acc0, 0, 0, 0); \
            acc1 = __builtin_amdgcn_mfma_f32_16x16x32_f16(a1, bb.v, acc1, 0, 0, 0); \
        }

    unsigned p0, p1, p2;
    POLL_ISSUE(p0); POLL_ISSUE(p1); POLL_ISSUE(p2);   // prime the poll ring

    for (int t = 0; t < T; ++t) {
        // ---- wait for h(t): pipelined 3-deep MALL poll ring, no sleep ----
        // flags are monotone; checking a stale ring slot is safe.
        if (t) {
            const unsigned tc = (unsigned)t;
            for (;;) {
                asm volatile("s_waitcnt vmcnt(2)" ::: "memory");
                __builtin_amdgcn_sched_barrier(0);
                if (__all((int)(p0 >= tc))) break;
                POLL_ISSUE(p0);
                asm volatile("s_waitcnt vmcnt(2)" ::: "memory");
                __builtin_amdgcn_sched_barrier(0);
                if (__all((int)(p1 >= tc))) break;
                POLL_ISSUE(p1);
                asm volatile("s_waitcnt vmcnt(2)" ::: "memory");
                __builtin_amdgcn_sched_barrier(0);
                if (__all((int)(p2 >= tc))) break;
                POLL_ISSUE(p2);
            }
        }
        __builtin_amdgcn_sched_barrier(0);
        // <=2 poll loads remain in flight; vmcnt completes oldest-first, so
        // the counted waits below absorb them conservatively.

        const ull rdb = (t & 1) ? hu1 : hu0;
        const ull wrb = (t & 1) ? hu0 : hu1;
        const ull rd  = rdb + (size_t)n * 2048 + kg * 16;

        u32x4 hA[8], hB[8];
        f32x4 acc0 = {0.f, 0.f, 0.f, 0.f};
        f32x4 acc1 = {0.f, 0.f, 0.f, 0.f};

        ISSUE8(hA, rd);
        ISSUE8(hB, rd + 512);
        asm volatile("s_waitcnt vmcnt(8)" ::: "memory");
        __builtin_amdgcn_sched_barrier(0);
        COMPUTE8(hA, 0);
        ISSUE8(hA, rd + 1024);
        asm volatile("s_waitcnt vmcnt(8)" ::: "memory");
        __builtin_amdgcn_sched_barrier(0);
        COMPUTE8(hB, 8);
        ISSUE8(hB, rd + 1536);
        asm volatile("s_waitcnt vmcnt(8)" ::: "memory");
        __builtin_amdgcn_sched_barrier(0);
        COMPUTE8(hA, 16);
        asm volatile("s_waitcnt vmcnt(0)" ::: "memory");
        __builtin_amdgcn_sched_barrier(0);
        COMPUTE8(hB, 24);

        // ---- epilogue: rank-1 input + bias + tanh; sc0 stores (-> own L2) ----
        const float xn = xT[(size_t)t * B + n];
        union { ull u; f16x4 v; } s0, s1;
        #pragma unroll
        for (int r = 0; r < 4; ++r)
            s0.v[r] = (_Float16)fast_tanh(acc0[r] + whx0[r] * xn + bhn);
        #pragma unroll
        for (int r = 0; r < 4; ++r)
            s1.v[r] = (_Float16)fast_tanh(acc1[r] + whx1[r] * xn + bhn);
        // h row-major [n][m]: s0 rows at m=base32+kg*4 (8B), s1 at m+16 (+32B)
        const ull wr = wrb + (size_t)n * 2048 + (size_t)(base32 + kg * 4) * 2;
        G_STORE_X2(wr, s0.u);
        G_STORE_X2(wr + 32, s1.u);

        // ---- signal: drain h stores, pre-issue next polls, publish flag ----
        asm volatile("s_waitcnt vmcnt(0)" ::: "memory");  // h acked in L2
        POLL_ISSUE(p0); POLL_ISSUE(p1); POLL_ISSUE(p2);   // overlap flag's MALL trip
        if (lane == 0)
            __hip_atomic_store(fme, (unsigned)(t + 1),
                               __ATOMIC_RELAXED, __HIP_MEMORY_SCOPE_AGENT);
        __builtin_amdgcn_sched_barrier(0);
    }
    #undef COMPUTE8
}

// ---- final projection: h plain row-major [B][H] ----
__global__ void proj_kernel(const _Float16* __restrict__ hT,
                            const float* __restrict__ Wph,
                            const float* __restrict__ bp,
                            float* __restrict__ out) {
    const int b = blockIdx.x;
    const int lane = threadIdx.x;  // 64
    float partial[NC];
    #pragma unroll
    for (int c = 0; c < NC; ++c) partial[c] = 0.f;
    for (int i = lane; i < H; i += 64) {
        float hv = (float)hT[(size_t)b * H + i];
        #pragma unroll
        for (int c = 0; c < NC; ++c) partial[c] += Wph[(size_t)c * H + i] * hv;
    }
    #pragma unroll
    for (int c = 0; c < NC; ++c) {
        float v = partial[c];
        #pragma unroll
        for (int off = 32; off; off >>= 1) v += __shfl_down(v, off);
        if (lane == 0) out[(size_t)b * NC + c] = v + bp[b];
    }
}

extern "C" void kernel_launch(void* const* d_in, const int* in_sizes, int n_in,
                              void* d_out, int out_size, void* d_ws, size_t ws_size,
                              hipStream_t stream) {
    const float* x   = (const float*)d_in[0];
    const float* Whx = (const float*)d_in[1];
    const float* Whh = (const float*)d_in[2];
    const float* Wph = (const float*)d_in[3];
    const float* bh  = (const float*)d_in[4];
    const float* bp  = (const float*)d_in[5];
    float* out = (float*)d_out;

    char* ws = (char*)d_ws;
    _Float16* Wf    = (_Float16*)ws;                     // 2 MB
    _Float16* h0    = (_Float16*)(ws + (2u << 20));      // 1 MB
    _Float16* h1    = (_Float16*)(ws + (3u << 20));      // 1 MB
    float*    xT    = (float*)(ws + (4u << 20));         // 1 MB
    unsigned* flags = (unsigned*)(ws + (5u << 20));      // 64 KB
    unsigned* claim = (unsigned*)(ws + (5u << 20) + 65536);

    convert_w<<<(H * H / 4) / 256, 256, 0, stream>>>(Whh, Wf);
    transpose_x<<<dim3(T / 32, B / 32), 256, 0, stream>>>(x, xT);
    hipMemsetAsync(h0, 0, (size_t)B * H * 2, stream);
    hipMemsetAsync(flags, 0, 65536 + 256, stream);

    rnn_persist<<<NGROUPS * WPG, 256, 0, stream>>>(Wf, xT, Whx, bh,
                                                   h0, h1, flags, claim);

    // T even -> final h in h0
    proj_kernel<<<B, 64, 0, stream>>>(h0, Wph, bp, out);
}

// Round 12
// 2962.837 us; speedup vs baseline: 2.7452x; 1.2150x over previous
//
#include <hip/hip_runtime.h>
#include <hip/hip_fp16.h>

#define H 1024
#define B 512
#define T 512
#define NC 10

#define NGROUPS 16      // batch-slice groups (32 batches each)
#define WPG 16          // WGs per group (M slices)
#define NSLICE 32       // batches per group
#define MROWS 64        // H rows per WG
#define FLAG_STRIDE 16  // 64B-padded flag per (WG,wave)

typedef _Float16 f16x8 __attribute__((ext_vector_type(8)));
typedef _Float16 f16x4 __attribute__((ext_vector_type(4)));
typedef float    f32x4 __attribute__((ext_vector_type(4)));
typedef unsigned u32x4 __attribute__((ext_vector_type(4)));
typedef unsigned long long ull;

__device__ __forceinline__ float fast_tanh(float x) {
    float e = __expf(2.0f * x);
    return 1.0f - 2.0f / (e + 1.0f);
}

// ---- W_hh f32 -> f16 row-major ----
__global__ void convert_w(const float* __restrict__ w, _Float16* __restrict__ o) {
    int i = (blockIdx.x * 256 + threadIdx.x) * 4;
    float4 v = *(const float4*)(w + i);
    f16x4 r;
    r[0] = (_Float16)v.x; r[1] = (_Float16)v.y;
    r[2] = (_Float16)v.z; r[3] = (_Float16)v.w;
    *(f16x4*)(o + i) = r;
}

// ---- x [B][T] -> xT [T][B] ----
__global__ void transpose_x(const float* __restrict__ x, float* __restrict__ xT) {
    __shared__ float tile[32][33];
    const int tx = threadIdx.x & 31;
    const int ty = threadIdx.x >> 5;
    const int t0 = blockIdx.x * 32;
    const int b0 = blockIdx.y * 32;
    #pragma unroll
    for (int i = ty; i < 32; i += 8)
        tile[i][tx] = x[(size_t)(b0 + i) * T + t0 + tx];
    __syncthreads();
    #pragma unroll
    for (int i = ty; i < 32; i += 8)
        xT[(size_t)(t0 + i) * B + b0 + tx] = tile[tx][i];
}

// h load: sc0 only -> bypass own stale L1, served by the XCD-shared L2
#define G_LOAD_X4(dst, addr, OFF) \
    asm volatile("global_load_dwordx4 %0, %1, off offset:" OFF " sc0" \
                 : "=&v"(dst) : "v"(addr) : "memory")

#define ISSUE8(arr, base) do { \
    G_LOAD_X4(arr[0], (base), "0");   G_LOAD_X4(arr[1], (base), "64");  \
    G_LOAD_X4(arr[2], (base), "128"); G_LOAD_X4(arr[3], (base), "192"); \
    G_LOAD_X4(arr[4], (base), "256"); G_LOAD_X4(arr[5], (base), "320"); \
    G_LOAD_X4(arr[6], (base), "384"); G_LOAD_X4(arr[7], (base), "448"); \
} while (0)

// h store: sc0 -> coherent write-through to the XCD-shared L2 (stops at L2)
#define G_STORE_X2(addr, data) \
    asm volatile("global_store_dwordx2 %0, %1, off sc0" \
                 :: "v"(addr), "v"(data) : "memory")

// ---- persistent RNN: 256 WGs x 256 thr (4 waves) ----
// R9 structure (h in XCD L2 via sc0 stores/loads; per-wave agent-scope flags).
// SINGLE change vs R9: two-level master/broadcast barrier.
//   master wave (ms==0, wm==0) per (group, wn): polls the 32 producer flags,
//   publishes ONE epoch word; all other waves poll that single hot line
//   (64 lanes, same address -> 1 line request/wave) => ~32x less MALL poll
//   traffic. Epoch=t implies all producer h stores are drained into L2.
__global__ void __launch_bounds__(256, 1) rnn_persist(
        const _Float16* __restrict__ Wf, const float* __restrict__ xT,
        const float* __restrict__ Whx, const float* __restrict__ bh,
        _Float16* h0, _Float16* h1,
        unsigned* flags, unsigned* epoch, unsigned* claim) {

    __shared__ _Float16 Wlds[MROWS * H];   // 128 KB -> exactly 1 WG/CU
    __shared__ int s_g, s_ms;

    const int tid  = threadIdx.x;
    const int wave = tid >> 6;
    const int lane = tid & 63;
    const int lm   = lane & 15;
    const int kg   = lane >> 4;
    const int wm   = wave >> 1;            // M half 0..1
    const int wn   = wave & 1;             // N half 0..1

    // ---- dynamic XCD grouping (capacity-forced: exactly 32 WGs per XCD) ----
    if (tid == 0) {
        unsigned xcd;
        asm volatile("s_getreg_b32 %0, hwreg(HW_REG_XCC_ID)" : "=s"(xcd));
        xcd &= 7;
        unsigned slot = atomicAdd(&claim[xcd], 1u);   // 0..31 per XCD
        s_ms = (int)(slot & 15);
        s_g  = (int)(xcd * 2 + (slot >> 4));
    }
    __syncthreads();
    const int g  = s_g;
    const int ms = s_ms;

    // ---- stage W rows [ms*64,+64) into fragment-order LDS ----
    for (int f = tid; f < MROWS * H / 8; f += 256) {
        const int p   = f >> 6;
        const int l   = f & 63;
        const int kkb = p >> 2;
        const int pwm = (p >> 1) & 1;
        const int prb = p & 1;
        const int pkg = l >> 4;
        const int plm = l & 15;
        const int m = ms * 64 + pwm * 32 + prb * 16 + plm;
        f16x8 v = *(const f16x8*)(Wf + (size_t)m * H + kkb * 32 + pkg * 8);
        *(f16x8*)((char*)Wlds + (size_t)f * 16) = v;
    }
    __syncthreads();   // once, before the loop

    // ---- per-lane constants ----
    const int n      = g * NSLICE + wn * 16 + lm;   // batch column
    const int base32 = ms * 64 + wm * 32;
    float whx0[4], whx1[4];
    #pragma unroll
    for (int r = 0; r < 4; ++r) {
        whx0[r] = Whx[base32 + kg * 4 + r];
        whx1[r] = Whx[base32 + 16 + kg * 4 + r];
    }
    const float bhn = bh[n];

    const ull hu0 = (ull)h0, hu1 = (ull)h1;
    const char* arow = (const char*)Wlds + wm * 2048 + lane * 16;

    // my flag: (g, ms, wm, wn); master polls producers (g, ms', wm', wn)
    unsigned* fme = flags +
        (size_t)((((g << 4) | ms) << 2) | (wm << 1) | wn) * FLAG_STRIDE;
    const unsigned* fpoll = flags +
        (size_t)((((g << 4) | ((lane >> 1) & 15)) << 2) | ((lane & 1) << 1) | wn)
        * FLAG_STRIDE;
    unsigned* eme = epoch + (size_t)((g << 1) | wn) * FLAG_STRIDE;
    const bool is_master = (ms == 0) && (wm == 0);

    #define COMPUTE8(arr, KB0)                                            \
        _Pragma("unroll")                                                 \
        for (int i = 0; i < 8; ++i) {                                     \
            f16x8 a0 = *(const f16x8*)(arow + (KB0 + i) * 4096);          \
            f16x8 a1 = *(const f16x8*)(arow + (KB0 + i) * 4096 + 1024);   \
            union { u32x4 u; f16x8 v; } bb; bb.u = arr[i];                \
            acc0 = __builtin_amdgcn_mfma_f32_16x16x32_f16(a0, bb.v, acc0, 0, 0, 0); \
            acc1 = __builtin_amdgcn_mfma_f32_16x16x32_f16(a1, bb.v, acc1, 0, 0, 0); \
        }

    for (int t = 0; t < T; ++t) {
        // ---- wait for h(t): master gathers 32 flags, broadcasts 1 epoch ----
        if (t) {
            const unsigned tc = (unsigned)t;
            if (is_master) {
                unsigned v;
                do {
                    __builtin_amdgcn_s_sleep(1);
                    v = __hip_atomic_load(fpoll, __ATOMIC_RELAXED,
                                          __HIP_MEMORY_SCOPE_AGENT);
                } while (!__all((int)(v >= tc)));
                if (lane == 0)
                    __hip_atomic_store(eme, tc,
                                       __ATOMIC_RELAXED, __HIP_MEMORY_SCOPE_AGENT);
            } else {
                unsigned e;
                do {
                    __builtin_amdgcn_s_sleep(1);
                    e = __hip_atomic_load(eme, __ATOMIC_RELAXED,
                                          __HIP_MEMORY_SCOPE_AGENT);
                } while (e < tc);
            }
        }
        __builtin_amdgcn_sched_barrier(0);

        const ull rdb = (t & 1) ? hu1 : hu0;
        const ull wrb = (t & 1) ? hu0 : hu1;
        const ull rd  = rdb + (size_t)n * 2048 + kg * 16;

        u32x4 hA[8], hB[8];
        f32x4 acc0 = {0.f, 0.f, 0.f, 0.f};
        f32x4 acc1 = {0.f, 0.f, 0.f, 0.f};

        ISSUE8(hA, rd);
        ISSUE8(hB, rd + 512);
        asm volatile("s_waitcnt vmcnt(8)" ::: "memory");
        __builtin_amdgcn_sched_barrier(0);
        COMPUTE8(hA, 0);
        ISSUE8(hA, rd + 1024);
        asm volatile("s_waitcnt vmcnt(8)" ::: "memory");
        __builtin_amdgcn_sched_barrier(0);
        COMPUTE8(hB, 8);
        ISSUE8(hB, rd + 1536);
        asm volatile("s_waitcnt vmcnt(8)" ::: "memory");
        __builtin_amdgcn_sched_barrier(0);
        COMPUTE8(hA, 16);
        asm volatile("s_waitcnt vmcnt(0)" ::: "memory");
        __builtin_amdgcn_sched_barrier(0);
        COMPUTE8(hB, 24);

        // ---- epilogue: rank-1 input + bias + tanh; sc0 stores (-> own L2) ----
        const float xn = xT[(size_t)t * B + n];
        union { ull u; f16x4 v; } s0, s1;
        #pragma unroll
        for (int r = 0; r < 4; ++r)
            s0.v[r] = (_Float16)fast_tanh(acc0[r] + whx0[r] * xn + bhn);
        #pragma unroll
        for (int r = 0; r < 4; ++r)
            s1.v[r] = (_Float16)fast_tanh(acc1[r] + whx1[r] * xn + bhn);
        // h row-major [n][m]: s0 rows at m=base32+kg*4 (8B), s1 at m+16 (+32B)
        const ull wr = wrb + (size_t)n * 2048 + (size_t)(base32 + kg * 4) * 2;
        G_STORE_X2(wr, s0.u);
        G_STORE_X2(wr + 32, s1.u);

        // ---- signal: h in L2 (acked) -> per-wave flag via agent atomic ----
        asm volatile("s_waitcnt vmcnt(0)" ::: "memory");  // reads+stores drained
        if (lane == 0)
            __hip_atomic_store(fme, (unsigned)(t + 1),
                               __ATOMIC_RELAXED, __HIP_MEMORY_SCOPE_AGENT);
        __builtin_amdgcn_sched_barrier(0);
    }
    #undef COMPUTE8
}

// ---- final projection: h plain row-major [B][H] ----
__global__ void proj_kernel(const _Float16* __restrict__ hT,
                            const float* __restrict__ Wph,
                            const float* __restrict__ bp,
                            float* __restrict__ out) {
    const int b = blockIdx.x;
    const int lane = threadIdx.x;  // 64
    float partial[NC];
    #pragma unroll
    for (int c = 0; c < NC; ++c) partial[c] = 0.f;
    for (int i = lane; i < H; i += 64) {
        float hv = (float)hT[(size_t)b * H + i];
        #pragma unroll
        for (int c = 0; c < NC; ++c) partial[c] += Wph[(size_t)c * H + i] * hv;
    }
    #pragma unroll
    for (int c = 0; c < NC; ++c) {
        float v = partial[c];
        #pragma unroll
        for (int off = 32; off; off >>= 1) v += __shfl_down(v, off);
        if (lane == 0) out[(size_t)b * NC + c] = v + bp[b];
    }
}

extern "C" void kernel_launch(void* const* d_in, const int* in_sizes, int n_in,
                              void* d_out, int out_size, void* d_ws, size_t ws_size,
                              hipStream_t stream) {
    const float* x   = (const float*)d_in[0];
    const float* Whx = (const float*)d_in[1];
    const float* Whh = (const float*)d_in[2];
    const float* Wph = (const float*)d_in[3];
    const float* bh  = (const float*)d_in[4];
    const float* bp  = (const float*)d_in[5];
    float* out = (float*)d_out;

    char* ws = (char*)d_ws;
    _Float16* Wf    = (_Float16*)ws;                     // 2 MB
    _Float16* h0    = (_Float16*)(ws + (2u << 20));      // 1 MB
    _Float16* h1    = (_Float16*)(ws + (3u << 20));      // 1 MB
    float*    xT    = (float*)(ws + (4u << 20));         // 1 MB
    unsigned* flags = (unsigned*)(ws + (5u << 20));                // 64 KB
    unsigned* epoch = (unsigned*)(ws + (5u << 20) + 65536);        // 2 KB
    unsigned* claim = (unsigned*)(ws + (5u << 20) + 65536 + 2048); // 256 B

    convert_w<<<(H * H / 4) / 256, 256, 0, stream>>>(Whh, Wf);
    transpose_x<<<dim3(T / 32, B / 32), 256, 0, stream>>>(x, xT);
    hipMemsetAsync(h0, 0, (size_t)B * H * 2, stream);
    hipMemsetAsync(flags, 0, 65536 + 2048 + 256, stream);

    rnn_persist<<<NGROUPS * WPG, 256, 0, stream>>>(Wf, xT, Whx, bh,
                                                   h0, h1, flags, epoch, claim);

    // T even -> final h in h0
    proj_kernel<<<B, 64, 0, stream>>>(h0, Wph, bp, out);
}

// Round 13
// 2730.195 us; speedup vs baseline: 2.9791x; 1.0852x over previous
//
#include <hip/hip_runtime.h>
#include <hip/hip_fp16.h>

#define H 1024
#define B 512
#define T 512
#define NC 10

#define NGROUPS 16      // batch-slice groups (32 batches each)
#define WPG 16          // WGs per group (M slices)
#define NSLICE 32       // batches per group
#define MROWS 64        // H rows per WG
#define FLAG_STRIDE 16  // 16 u32 = 64B per flag line

typedef _Float16 f16x8 __attribute__((ext_vector_type(8)));
typedef _Float16 f16x4 __attribute__((ext_vector_type(4)));
typedef float    f32x4 __attribute__((ext_vector_type(4)));
typedef unsigned u32x4 __attribute__((ext_vector_type(4)));
typedef unsigned long long ull;

__device__ __forceinline__ float fast_tanh(float x) {
    float e = __expf(2.0f * x);
    return 1.0f - 2.0f / (e + 1.0f);
}

// ---- W_hh f32 -> f16 row-major ----
__global__ void convert_w(const float* __restrict__ w, _Float16* __restrict__ o) {
    int i = (blockIdx.x * 256 + threadIdx.x) * 4;
    float4 v = *(const float4*)(w + i);
    f16x4 r;
    r[0] = (_Float16)v.x; r[1] = (_Float16)v.y;
    r[2] = (_Float16)v.z; r[3] = (_Float16)v.w;
    *(f16x4*)(o + i) = r;
}

// ---- x [B][T] -> xT [T][B] ----
__global__ void transpose_x(const float* __restrict__ x, float* __restrict__ xT) {
    __shared__ float tile[32][33];
    const int tx = threadIdx.x & 31;
    const int ty = threadIdx.x >> 5;
    const int t0 = blockIdx.x * 32;
    const int b0 = blockIdx.y * 32;
    #pragma unroll
    for (int i = ty; i < 32; i += 8)
        tile[i][tx] = x[(size_t)(b0 + i) * T + t0 + tx];
    __syncthreads();
    #pragma unroll
    for (int i = ty; i < 32; i += 8)
        xT[(size_t)(t0 + i) * B + b0 + tx] = tile[tx][i];
}

// h load: sc0 only -> bypass own stale L1, served by the XCD-shared L2
#define G_LOAD_X4(dst, addr, OFF) \
    asm volatile("global_load_dwordx4 %0, %1, off offset:" OFF " sc0" \
                 : "=&v"(dst) : "v"(addr) : "memory")

#define ISSUE8(arr, base) do { \
    G_LOAD_X4(arr[0], (base), "0");   G_LOAD_X4(arr[1], (base), "64");  \
    G_LOAD_X4(arr[2], (base), "128"); G_LOAD_X4(arr[3], (base), "192"); \
    G_LOAD_X4(arr[4], (base), "256"); G_LOAD_X4(arr[5], (base), "320"); \
    G_LOAD_X4(arr[6], (base), "384"); G_LOAD_X4(arr[7], (base), "448"); \
} while (0)

// h store: sc0 -> coherent write-through to the XCD-shared L2 (stops at L2)
#define G_STORE_X2(addr, data) \
    asm volatile("global_store_dwordx2 %0, %1, off sc0" \
                 :: "v"(addr), "v"(data) : "memory")

// flag poll: agent-scope load (MALL) — proven prompt-visibility path
#define PISSUE(v) \
    asm volatile("global_load_dword %0, %1, off sc0 sc1" \
                 : "=&v"(v) : "v"(fpoll) : "memory")

// ---- persistent RNN: 256 WGs x 256 thr (4 waves) ----
// R9/R12 structure (h in XCD L2 via sc0; dynamic XCD grouping; W in LDS).
// NEW barrier: per-WG flags REPLICATED per consumer (16 private lines/WG,
// <=1 polling wave per line -> zero MALL line-sharing), ONE MALL hop,
// sleep-free dual-chain pipelined poll by wave 0 only; other waves held by
// __syncthreads. flag(P)=t+1 certifies P's whole-WG h(t+1) drained into L2.
__global__ void __launch_bounds__(256, 1) rnn_persist(
        const _Float16* __restrict__ Wf, const float* __restrict__ xT,
        const float* __restrict__ Whx, const float* __restrict__ bh,
        _Float16* h0, _Float16* h1, unsigned* flags, unsigned* claim) {

    __shared__ _Float16 Wlds[MROWS * H];   // 128 KB -> exactly 1 WG/CU
    __shared__ int s_g, s_ms;

    const int tid  = threadIdx.x;
    const int wave = tid >> 6;
    const int lane = tid & 63;
    const int lm   = lane & 15;
    const int kg   = lane >> 4;
    const int wm   = wave >> 1;            // M half 0..1
    const int wn   = wave & 1;             // N half 0..1

    // ---- dynamic XCD grouping (capacity-forced: exactly 32 WGs per XCD) ----
    if (tid == 0) {
        unsigned xcd;
        asm volatile("s_getreg_b32 %0, hwreg(HW_REG_XCC_ID)" : "=s"(xcd));
        xcd &= 7;
        unsigned slot = atomicAdd(&claim[xcd], 1u);   // 0..31 per XCD
        s_ms = (int)(slot & 15);
        s_g  = (int)(xcd * 2 + (slot >> 4));
    }
    __syncthreads();
    const int g  = s_g;
    const int ms = s_ms;

    // ---- stage W rows [ms*64,+64) into fragment-order LDS ----
    for (int f = tid; f < MROWS * H / 8; f += 256) {
        const int p   = f >> 6;
        const int l   = f & 63;
        const int kkb = p >> 2;
        const int pwm = (p >> 1) & 1;
        const int prb = p & 1;
        const int pkg = l >> 4;
        const int plm = l & 15;
        const int m = ms * 64 + pwm * 32 + prb * 16 + plm;
        f16x8 v = *(const f16x8*)(Wf + (size_t)m * H + kkb * 32 + pkg * 8);
        *(f16x8*)((char*)Wlds + (size_t)f * 16) = v;
    }
    __syncthreads();   // once, before the loop

    // ---- per-lane constants ----
    const int n      = g * NSLICE + wn * 16 + lm;   // batch column
    const int base32 = ms * 64 + wm * 32;
    float whx0[4], whx1[4];
    #pragma unroll
    for (int r = 0; r < 4; ++r) {
        whx0[r] = Whx[base32 + kg * 4 + r];
        whx1[r] = Whx[base32 + 16 + kg * 4 + r];
    }
    const float bhn = bh[n];

    const ull hu0 = (ull)h0, hu1 = (ull)h1;
    const char* arow = (const char*)Wlds + wm * 2048 + lane * 16;

    // flag block layout: [group][consumer_ms][producer_ms] x 64B lines.
    // I poll MY block (g, ms): lane l -> producer line l&15 (<=1 WG per line).
    // I publish to 16 replicas: lane<16 -> block (g, lane), slot ms.
    const ull fpoll = (ull)(flags +
        (size_t)((((g << 4) | ms) << 4) | (lane & 15)) * FLAG_STRIDE);
    unsigned* fpub = flags +
        (size_t)((((g << 4) | (lane & 15)) << 4) | ms) * FLAG_STRIDE;

    #define COMPUTE8(arr, KB0)                                            \
        _Pragma("unroll")                                                 \
        for (int i = 0; i < 8; ++i) {                                     \
            f16x8 a0 = *(const f16x8*)(arow + (KB0 + i) * 4096);          \
            f16x8 a1 = *(const f16x8*)(arow + (KB0 + i) * 4096 + 1024);   \
            union { u32x4 u; f16x8 v; } bb; bb.u = arr[i];                \
            acc0 = __builtin_amdgcn_mfma_f32_16x16x32_f16(a0, bb.v, acc0, 0, 0, 0); \
            acc1 = __builtin_amdgcn_mfma_f32_16x16x32_f16(a1, bb.v, acc1, 0, 0, 0); \
        }

    for (int t = 0; t < T; ++t) {
        // ---- wait for h(t): wave 0 dual-chain pipelined poll, no sleep ----
        // Invariant: the register checked is never the newest outstanding
        // load, and vmcnt(1) guarantees its load retired. Flags are monotone,
        // so stale values can only fail (retry) or be truly satisfied.
        if (wave == 0 && t) {
            const unsigned tc = (unsigned)t;
            unsigned va, vb;
            PISSUE(va); PISSUE(vb);
            for (;;) {
                asm volatile("s_waitcnt vmcnt(1)" ::: "memory");
                __builtin_amdgcn_sched_barrier(0);
                if (__all((int)(va >= tc))) break;
                PISSUE(va);
                asm volatile("s_waitcnt vmcnt(1)" ::: "memory");
                __builtin_amdgcn_sched_barrier(0);
                if (__all((int)(vb >= tc))) break;
                PISSUE(vb);
            }
        }
        __syncthreads();   // release all 4 waves: h(t) readable in L2
        __builtin_amdgcn_sched_barrier(0);

        const ull rdb = (t & 1) ? hu1 : hu0;
        const ull wrb = (t & 1) ? hu0 : hu1;
        const ull rd  = rdb + (size_t)n * 2048 + kg * 16;

        u32x4 hA[8], hB[8];
        f32x4 acc0 = {0.f, 0.f, 0.f, 0.f};
        f32x4 acc1 = {0.f, 0.f, 0.f, 0.f};

        ISSUE8(hA, rd);
        ISSUE8(hB, rd + 512);
        asm volatile("s_waitcnt vmcnt(8)" ::: "memory");
        __builtin_amdgcn_sched_barrier(0);
        COMPUTE8(hA, 0);
        ISSUE8(hA, rd + 1024);
        asm volatile("s_waitcnt vmcnt(8)" ::: "memory");
        __builtin_amdgcn_sched_barrier(0);
        COMPUTE8(hB, 8);
        ISSUE8(hB, rd + 1536);
        asm volatile("s_waitcnt vmcnt(8)" ::: "memory");
        __builtin_amdgcn_sched_barrier(0);
        COMPUTE8(hA, 16);
        asm volatile("s_waitcnt vmcnt(0)" ::: "memory");
        __builtin_amdgcn_sched_barrier(0);
        COMPUTE8(hB, 24);

        // ---- epilogue: rank-1 input + bias + tanh; sc0 stores (-> own L2) ----
        const float xn = xT[(size_t)t * B + n];
        union { ull u; f16x4 v; } s0, s1;
        #pragma unroll
        for (int r = 0; r < 4; ++r)
            s0.v[r] = (_Float16)fast_tanh(acc0[r] + whx0[r] * xn + bhn);
        #pragma unroll
        for (int r = 0; r < 4; ++r)
            s1.v[r] = (_Float16)fast_tanh(acc1[r] + whx1[r] * xn + bhn);
        // h row-major [n][m]: s0 rows at m=base32+kg*4 (8B), s1 at m+16 (+32B)
        const ull wr = wrb + (size_t)n * 2048 + (size_t)(base32 + kg * 4) * 2;
        G_STORE_X2(wr, s0.u);
        G_STORE_X2(wr + 32, s1.u);

        // ---- publish: all waves drained -> wave0 fans out 16 replicas ----
        asm volatile("s_waitcnt vmcnt(0)" ::: "memory");  // reads+stores drained
        __syncthreads();                                  // whole WG drained
        if (wave == 0 && lane < 16)
            __hip_atomic_store(fpub, (unsigned)(t + 1),
                               __ATOMIC_RELAXED, __HIP_MEMORY_SCOPE_AGENT);
        __builtin_amdgcn_sched_barrier(0);
    }
    #undef COMPUTE8
}

// ---- final projection: h plain row-major [B][H] ----
__global__ void proj_kernel(const _Float16* __restrict__ hT,
                            const float* __restrict__ Wph,
                            const float* __restrict__ bp,
                            float* __restrict__ out) {
    const int b = blockIdx.x;
    const int lane = threadIdx.x;  // 64
    float partial[NC];
    #pragma unroll
    for (int c = 0; c < NC; ++c) partial[c] = 0.f;
    for (int i = lane; i < H; i += 64) {
        float hv = (float)hT[(size_t)b * H + i];
        #pragma unroll
        for (int c = 0; c < NC; ++c) partial[c] += Wph[(size_t)c * H + i] * hv;
    }
    #pragma unroll
    for (int c = 0; c < NC; ++c) {
        float v = partial[c];
        #pragma unroll
        for (int off = 32; off; off >>= 1) v += __shfl_down(v, off);
        if (lane == 0) out[(size_t)b * NC + c] = v + bp[b];
    }
}

extern "C" void kernel_launch(void* const* d_in, const int* in_sizes, int n_in,
                              void* d_out, int out_size, void* d_ws, size_t ws_size,
                              hipStream_t stream) {
    const float* x   = (const float*)d_in[0];
    const float* Whx = (const float*)d_in[1];
    const float* Whh = (const float*)d_in[2];
    const float* Wph = (const float*)d_in[3];
    const float* bh  = (const float*)d_in[4];
    const float* bp  = (const float*)d_in[5];
    float* out = (float*)d_out;

    char* ws = (char*)d_ws;
    _Float16* Wf    = (_Float16*)ws;                     // 2 MB
    _Float16* h0    = (_Float16*)(ws + (2u << 20));      // 1 MB
    _Float16* h1    = (_Float16*)(ws + (3u << 20));      // 1 MB
    float*    xT    = (float*)(ws + (4u << 20));         // 1 MB
    unsigned* flags = (unsigned*)(ws + (5u << 20));      // 16*16*16 x 64B = 256 KB
    unsigned* claim = (unsigned*)(ws + (5u << 20) + 262144);

    convert_w<<<(H * H / 4) / 256, 256, 0, stream>>>(Whh, Wf);
    transpose_x<<<dim3(T / 32, B / 32), 256, 0, stream>>>(x, xT);
    hipMemsetAsync(h0, 0, (size_t)B * H * 2, stream);
    hipMemsetAsync(flags, 0, 262144 + 256, stream);

    rnn_persist<<<NGROUPS * WPG, 256, 0, stream>>>(Wf, xT, Whx, bh,
                                                   h0, h1, flags, claim);

    // T even -> final h in h0
    proj_kernel<<<B, 64, 0, stream>>>(h0, Wph, bp, out);
}